// Round 6
// baseline (248.707 us; speedup 1.0000x reference)
//
#include <hip/hip_runtime.h>
#include <hip/hip_fp16.h>
#include <math.h>

// Caps1D dynamic routing — fp16 W records (repack prepass), dot2
// build+sweep, LDS u_ji, 1024-THREAD blocks (32 waves/CU), three-stream
// named-register prefetch build.
//
// u: [B=1024, R=2336, M=4] fp32 ; W: [K=2, R=2336, M=4, P=16] fp32
// out[b,k] = norm/(1+norm) of final squashed routing sum.
//
// Measured history: r8 W-coalescing (162->112us), r10 prefetch+dist-squash
// (->85), r11 dot2 sweep (->77), r15 two-stream (->70), r18 three-stream
// (127.6 total, routing ~70).
// r19 FAILED (143.9): DPP rewrite GOOD (bank confl 1.79M->0) but (512,4)
//   => 64-VGPR cap + hoisted raw[] => 77MB scratch spills.
// r20 BEST (121.7 total, routing 62-65): DPP kept, VGPR 60, VALU 58-61%.
// r21 FAILED (135.4): 4-stream + hoist -> VGPR 76 -> 64-VGPR OCCUPANCY
//   CLIFF (2 blocks/CU -> 1). HARD RULE: <=64 VGPR.
// r22 (120.8, routing 61.6-65.1): r20 restore, stable baseline.
// r23 FAILED (157.7, routing 104-108): single-kernel direct-fp32 W build.
//   5 loads/row vs 2, dependency-latency-bound (VALUBusy 30%). LESSON:
//   gap analysis says repack + extra node = only ~7us; ~50us of the
//   total-routing gap is fixed harness overhead. Keep two-kernel form.
// r24 (this): 1024-THREAD blocks. Occupancy was LDS-capped at 2 blocks/CU
//   (uji 74.7KB); at 512 thr that's only 16 waves/CU (4/SIMD). 1024 thr
//   keeps 2 blocks/CU but doubles TLP to 32 waves/CU (8/SIMD), which is
//   exactly what the 43% VALU-idle (build HBM latency) needs. The 8/SIMD
//   state imposes a 64-VGPR cap — affordable NOW because the DPP-rewrite
//   kernel demands only ~60 (r2-4/r9 failed this with the old >64-demand
//   code), and 16-wave sweep halves raw[] transients (raw[4] vs raw[9]).
//   __launch_bounds__(1024,8): k = 8*4/(1024/64) = 2 blocks/CU.
//   Tripwires: WRITE_SIZE balloons => spilling at the cap => revert r22;
//   occ ~38% => 1 block/CU => revert.
// FAILED branches (all measured): register-resident u_ji (r16), 768-thr
// (r17), sched_barrier fences (r14), array-chunk pipelines (r11/r12),
// raw[] hoist (r19/r21), VGPR>64 (r21), fused direct-fp32 build (r23).
// RULES (r12): arrays fully-unrolled constant-indexed, unconditionally
// initialized, no whole-array punning.

#define THREADS 1024
#define NWAVE 16
#define RR 2336
#define KK 2

#if __has_builtin(__builtin_amdgcn_fdot2)
typedef _Float16 h2v __attribute__((ext_vector_type(2)));
static __device__ __forceinline__ float dot2h(__half2 a, __half2 b, float c) {
    h2v av, bv;
    __builtin_memcpy(&av, &a, 4);
    __builtin_memcpy(&bv, &b, 4);
    return __builtin_amdgcn_fdot2(av, bv, c, false);
}
#else
static __device__ __forceinline__ float dot2h(__half2 a, __half2 b, float c) {
    float2 fa = __half22float2(a), fb = __half22float2(b);
    return fmaf(fa.x, fb.x, fmaf(fa.y, fb.y, c));
}
#endif

// ---- cross-lane add helpers (VALU-pipe DPP where possible) ----
#define DPP_XOR1 0xB1   // quad_perm [1,0,3,2]
#define DPP_XOR2 0x4E   // quad_perm [2,3,0,1]
#define DPP_ROR4 0x124  // row_ror:4
#define DPP_ROR8 0x128  // row_ror:8

template <int CTRL>
static __device__ __forceinline__ float dpp_addf(float x) {
    const int y = __builtin_amdgcn_update_dpp(0, __float_as_int(x), CTRL, 0xf, 0xf, true);
    return x + __int_as_float(y);
}
static __device__ __forceinline__ float swz16_addf(float x) {   // xor 16
    const int y = __builtin_amdgcn_ds_swizzle(__float_as_int(x), 0x401f);
    return x + __int_as_float(y);
}
#if __has_builtin(__builtin_amdgcn_permlane32_swap)
static __device__ __forceinline__ float pl32_addf(float x) {    // xor 32
    typedef unsigned uv2 __attribute__((ext_vector_type(2)));
    const uv2 r = __builtin_amdgcn_permlane32_swap(__float_as_uint(x), __float_as_uint(x),
                                                   false, false);
    return __uint_as_float(r[0]) + __uint_as_float(r[1]);
}
#else
static __device__ __forceinline__ float pl32_addf(float x) { return x + __shfl_xor(x, 32); }
#endif

// ---- prepass: W fp32 [k][r][m][p] -> records {w01x,w23x,w01y,w23y} ----
// record j = (k*RR + r)*8 + p2, 4 half2 = 16 B.
__global__ __launch_bounds__(256)
void w_repack_kernel(const float* __restrict__ W, __half2* __restrict__ Wt)
{
    const int n = KK * RR * 8;                   // 37376 records
    for (int j = blockIdx.x * 256 + threadIdx.x; j < n; j += gridDim.x * 256) {
        const int p2 = j & 7;
        const int rk = j >> 3;                   // k*RR + r
        const float* wp = W + (size_t)rk * 64;   // [m][p], 64 floats
        const float x0 = wp[0*16 + 2*p2],     x1 = wp[1*16 + 2*p2];
        const float x2 = wp[2*16 + 2*p2],     x3 = wp[3*16 + 2*p2];
        const float y0 = wp[0*16 + 2*p2 + 1], y1 = wp[1*16 + 2*p2 + 1];
        const float y2 = wp[2*16 + 2*p2 + 1], y3 = wp[3*16 + 2*p2 + 1];
        __half2* o = Wt + (size_t)j * 4;
        o[0] = __floats2half2_rn(x0, x1);
        o[1] = __floats2half2_rn(x2, x3);
        o[2] = __floats2half2_rn(y0, y1);
        o[3] = __floats2half2_rn(y2, y3);
    }
}

// one stream's compute step (named scalars only)
#define STREAM_COMP(base, i, uu, wv)                                   \
    {                                                                  \
        const int r = (base) + (i) * 128 + rbase;                      \
        const __half2 u01 = __floats2half2_rn(uu.x, uu.y);             \
        const __half2 u23 = __floats2half2_rn(uu.z, uu.w);             \
        const __half2* hm = (const __half2*)&wv;                       \
        const float ax = dot2h(u01, hm[0], dot2h(u23, hm[1], 0.0f));   \
        const float ay = dot2h(u01, hm[2], dot2h(u23, hm[3], 0.0f));   \
        sA += ax; sB += ay;                                            \
        *(__half2*)(uji + r * 16 + p2 * 2) = __floats2half2_rn(ax, ay); \
    }

// one routing-sweep step over a 16B half-row held in rw
#define SWEEP_STEP(rw)                                                     \
    {                                                                      \
        const __half2* hp = (const __half2*)&(rw);                         \
        float d = dot2h(hp[0], v2[0], dot2h(hp[1], v2[1],                  \
                  dot2h(hp[2], v2[2], dot2h(hp[3], v2[3], 0.0f))));        \
        d = dpp_addf<DPP_XOR1>(d);           /* join the two half-dots */  \
        const float e = __expf(d);           /* no max-subtract (bounded)*/\
        se += e;                                                           \
        { const float2 f0 = __half22float2(hp[0]);                         \
          s8[0] = fmaf(f0.x, e, s8[0]); s8[1] = fmaf(f0.y, e, s8[1]); }    \
        { const float2 f1 = __half22float2(hp[1]);                         \
          s8[2] = fmaf(f1.x, e, s8[2]); s8[3] = fmaf(f1.y, e, s8[3]); }    \
        { const float2 f2 = __half22float2(hp[2]);                         \
          s8[4] = fmaf(f2.x, e, s8[4]); s8[5] = fmaf(f2.y, e, s8[5]); }    \
        { const float2 f3 = __half22float2(hp[3]);                         \
          s8[6] = fmaf(f3.x, e, s8[6]); s8[7] = fmaf(f3.y, e, s8[7]); }    \
    }

__global__ __launch_bounds__(THREADS, 8)
void caps_routing_kernel(const float* __restrict__ u,
                         const __half2* __restrict__ Wt,
                         float* __restrict__ out)
{
    __shared__ __align__(16) __half uji[RR * 16];      // 74752 B
    __shared__ __align__(16) float  red[2][NWAVE][20]; // 2560 B
    __shared__ __align__(16) float  vrow[2][16];       // 128 B  (total 77440)

    const int bi   = blockIdx.x;                 // 2048 blocks
    const int b    = bi >> 1;
    const int k    = bi & 1;
    const int tid  = threadIdx.x;
    const int lane = tid & 63;
    const int wave = tid >> 6;                   // 0..15
    const int p2   = lane & 7;                   // half2 column pair 0..7
    const int g    = lane >> 3;                  // row-in-group 0..7

    const float4* __restrict__ u4p = (const float4*)u;
    const float4* __restrict__ w4t = (const float4*)Wt + (size_t)k * RR * 8 + p2;

    // ---- build u_ji (fp16 -> LDS) + iter-0 sums; THREE-stream prefetch ----
    // 16 waves cover 128 rows/step; streams A/B/C rows [0,768)/[768,1536)/
    // [1536,2304), 6 steps each, guard-free; tail rows 2304..2335 = waves
    // 0..3 (wave-uniform).
    float sA = 0.0f, sB = 0.0f;
    {
        const int rbase = wave * 8 + g;          // 0..127
        float4 uuA_n = u4p[b * RR + rbase];
        float4 wvA_n = w4t[(size_t)rbase * 8];
        float4 uuB_n = u4p[b * RR + 768 + rbase];
        float4 wvB_n = w4t[(size_t)(768 + rbase) * 8];
        float4 uuC_n = u4p[b * RR + 1536 + rbase];
        float4 wvC_n = w4t[(size_t)(1536 + rbase) * 8];
        #pragma unroll 3
        for (int i = 0; i < 6; ++i) {
            const float4 uuA = uuA_n, wvA = wvA_n;
            const float4 uuB = uuB_n, wvB = wvB_n;
            const float4 uuC = uuC_n, wvC = wvC_n;
            if (i + 1 < 6) {                     // prefetch all three streams
                const int ra = (i + 1) * 128 + rbase;
                uuA_n = u4p[b * RR + ra];
                wvA_n = w4t[(size_t)ra * 8];
                const int rb = 768 + ra;
                uuB_n = u4p[b * RR + rb];
                wvB_n = w4t[(size_t)rb * 8];
                const int rc = 1536 + ra;
                uuC_n = u4p[b * RR + rc];
                wvC_n = w4t[(size_t)rc * 8];
            }
            STREAM_COMP(0,    i, uuA, wvA)
            STREAM_COMP(768,  i, uuB, wvB)
            STREAM_COMP(1536, i, uuC, wvC)
        }
        if (wave < 4) {                          // tail rows 2304..2335
            const int r = 2304 + rbase;          // rbase < 32 here
            const float4 uu = u4p[b * RR + r];
            const float4 wv = w4t[(size_t)r * 8];
            const __half2 u01 = __floats2half2_rn(uu.x, uu.y);
            const __half2 u23 = __floats2half2_rn(uu.z, uu.w);
            const __half2* hm = (const __half2*)&wv;
            const float ax = dot2h(u01, hm[0], dot2h(u23, hm[1], 0.0f));
            const float ay = dot2h(u01, hm[2], dot2h(u23, hm[3], 0.0f));
            sA += ax; sB += ay;
            *(__half2*)(uji + r * 16 + p2 * 2) = __floats2half2_rn(ax, ay);
        }
    }
    // iter-0 partials: reduce over g (ror8 / swizzle-xor16 / permlane-xor32;
    // all preserve p2 = lane&7)
    sA = dpp_addf<DPP_ROR8>(sA);  sB = dpp_addf<DPP_ROR8>(sB);
    sA = swz16_addf(sA);          sB = swz16_addf(sB);
    sA = pl32_addf(sA);           sB = pl32_addf(sB);
    if (lane < 8) {
        red[0][wave][2 * p2]     = sA;
        red[0][wave][2 * p2 + 1] = sB;
    }
    __syncthreads();                             // barrier 1: uji + red[0] ready

    // ---- distributed squash, iter 0 (se == RR exactly); all-lane form ----
    float vcum_s;                                // this lane's cumulative v[lane&15]
    {
        float col = 0.0f;
        #pragma unroll
        for (int w = 0; w < NWAVE; ++w) col += red[0][w][lane & 15];
        float nr = col * col;
        nr = dpp_addf<DPP_XOR1>(nr);
        nr = dpp_addf<DPP_XOR2>(nr);
        nr = dpp_addf<DPP_ROR4>(nr);
        nr = dpp_addf<DPP_ROR8>(nr);             // row-replicated full 16-sum
        const float inv  = 1.0f / (float)RR;
        const float norm = nr * inv * inv;
        const float f    = sqrtf(norm) / (1.0f + norm);
        vcum_s = col * inv * f;
        if (lane < 16) vrow[0][lane] = vcum_s;   // benign same-value multi-wave write
    }

    // ---- iterations 1,2: sweep + distributed squash ----
    #pragma unroll 1
    for (int it = 1; it < 3; ++it) {
        const int buf = it & 1;

        __half2 v2[4];
        {
            const float2* vp = (const float2*)vrow[buf ^ 1];
            #pragma unroll
            for (int q = 0; q < 4; ++q) {
                const float2 pv = vp[(lane & 1) * 4 + q];
                v2[q] = __floats2half2_rn(pv.x, pv.y);
            }
        }

        // u_ji row slice: 16 waves cover 512 rows/step; steps 0..3
        // guard-free (max row 2047); step 4 = rows 2048..2335, waves 0..8
        // (wave-uniform), load clamped to stay inside uji.
        float4 raw[4], raw4;
        {
            const int rb = wave * 32 + (lane >> 1);      // 0..511
            #pragma unroll
            for (int s = 0; s < 4; ++s)
                raw[s] = *(const float4*)((const char*)uji + (s * 512 + rb) * 32 + (lane & 1) * 16);
            int rowt = 2048 + rb;
            rowt = (rowt < RR) ? rowt : (RR - 1);
            raw4 = *(const float4*)((const char*)uji + rowt * 32 + (lane & 1) * 16);
        }

        float s8[8] = {0, 0, 0, 0, 0, 0, 0, 0};
        float se = 0.0f;
        #pragma unroll
        for (int s = 0; s < 4; ++s) SWEEP_STEP(raw[s])
        if (wave < 9) SWEEP_STEP(raw4)           // wave-uniform tail step

        // parity-preserving reduction: 3 DPP + 1 swizzle + 1 permlane per var
        #pragma unroll
        for (int i = 0; i < 8; ++i) {
            s8[i] = dpp_addf<DPP_XOR2>(s8[i]);
            s8[i] = dpp_addf<DPP_ROR4>(s8[i]);
            s8[i] = dpp_addf<DPP_ROR8>(s8[i]);
            s8[i] = swz16_addf(s8[i]);
            s8[i] = pl32_addf(s8[i]);
        }
        se = dpp_addf<DPP_XOR2>(se);
        se = dpp_addf<DPP_ROR4>(se);
        se = dpp_addf<DPP_ROR8>(se);
        se = swz16_addf(se);
        se = pl32_addf(se);

        if (lane < 2) {
            *(float4*)&red[buf][wave][(lane & 1) * 8]     = make_float4(s8[0], s8[1], s8[2], s8[3]);
            *(float4*)&red[buf][wave][(lane & 1) * 8 + 4] = make_float4(s8[4], s8[5], s8[6], s8[7]);
            if (lane == 0) red[buf][wave][16] = se;
        }
        __syncthreads();                         // barrier 2 / 3

        // distributed squash from red[buf] (all-lane form)
        {
            float col = 0.0f, set = 0.0f;
            #pragma unroll
            for (int w = 0; w < NWAVE; ++w) {
                col += red[buf][w][lane & 15];
                set += red[buf][w][16];          // broadcast reads
            }
            float nr = col * col;
            nr = dpp_addf<DPP_XOR1>(nr);
            nr = dpp_addf<DPP_XOR2>(nr);
            nr = dpp_addf<DPP_ROR4>(nr);
            nr = dpp_addf<DPP_ROR8>(nr);
            const float inv  = 1.0f / set;
            const float norm = nr * inv * inv;
            if (it == 1) {
                const float f = sqrtf(norm) / (1.0f + norm);
                vcum_s += col * inv * f;
                if (lane < 16) vrow[1][lane] = vcum_s;
            } else if (wave == 0 && lane == 0) {
                out[b * KK + k] = norm / (1.0f + norm);
            }
        }
    }
}

extern "C" void kernel_launch(void* const* d_in, const int* in_sizes, int n_in,
                              void* d_out, int out_size, void* d_ws, size_t ws_size,
                              hipStream_t stream) {
    const float* u = (const float*)d_in[0];   // [1024, 2336, 4]
    const float* W = (const float*)d_in[1];   // [2, 2336, 4, 16]
    float* out = (float*)d_out;               // [1024, 2]
    __half2* Wt = (__half2*)d_ws;             // W records scratch

    w_repack_kernel<<<dim3(256), dim3(256), 0, stream>>>(W, Wt);
    caps_routing_kernel<<<dim3(2048), dim3(THREADS), 0, stream>>>(u, Wt, out);
}

// Round 7
// 120.609 us; speedup vs baseline: 2.0621x; 2.0621x over previous
//
#include <hip/hip_runtime.h>
#include <hip/hip_fp16.h>
#include <math.h>

// Caps1D dynamic routing — fp16 W records, dot2 build+sweep, LDS u_ji,
// THREE-STREAM named-register prefetch build (6 loads in flight).
// r25 = r22 (verified best) + exp2-fold + wave0-guarded tail load.
//
// u: [B=1024, R=2336, M=4] fp32 ; W: [K=2, R=2336, M=4, P=16] fp32
// out[b,k] = norm/(1+norm) of final squashed routing sum.
//
// Measured history: r8 W-coalescing (162->112us), r10 prefetch+dist-squash
// (->85), r11 dot2 sweep (->77), r15 two-stream (->70), r18 three-stream
// (127.6 total, routing ~70).
// r19 FAILED (143.9): DPP rewrite GOOD (confl 1.79M->0) but (512,4) =>
//   64-VGPR cap + hoisted raw[] => 77MB scratch spills.
// r20 BEST (121.7 total, routing 62-65): DPP kept. VGPR 60, VALU 58-61%.
// r21 FAILED (135.4): VGPR 76 -> 64-VGPR OCCUPANCY CLIFF (occ 37->21%).
//   HARD RULE: <=64 VGPR at 512 thr.
// r22 (120.8, routing 61.6-65.1): r20 restore, stable; confirmed twice.
// r23 FAILED (157.7, routing 104-108): fused direct-fp32 W build is
//   dependency-latency-bound (5 loads/row, VALUBusy 30%). Gap analysis:
//   repack+node = ~7us; ~50us of total-routing gap is fixed harness cost.
// r24 FAILED (248.7, routing 184): 1024-thr + (1024,8) => compiler
//   allocated 32 VGPR, total spill (WRITE 313MB). occ hit 80% proving the
//   TLP mechanism, but 1024-thr is triply-dead (r2-4, r9, r24).
// STRUCTURAL SPACE EXHAUSTED (all measured): VGPR>64, 768/1024-thr,
//   fusion, raw hoist, register u_ji, sched_barrier, array pipelines.
//   512 thr x 2 blocks/CU (16 waves) is the occupancy optimum under the
//   irreducible 74.7KB u_ji tile.
// r25 (this): r22 + two budget-neutral trims —
//   * exp2-fold: v2 pack pre-scales v by log2(e) (fp32 mul before fp16
//     round); sweep uses __builtin_amdgcn_exp2f directly. -10 v_mul/iter.
//   * raw9 tail row loaded AND consumed only by wave 0 (-1 ds_read for
//     7/8 waves per iter).
// RULES (r12): arrays fully-unrolled constant-indexed, unconditionally
// initialized, no whole-array punning. 512 thr + launch_bounds(512,2).

#define THREADS 512
#define NWAVE 8
#define RR 2336
#define KK 2

#if __has_builtin(__builtin_amdgcn_fdot2)
typedef _Float16 h2v __attribute__((ext_vector_type(2)));
static __device__ __forceinline__ float dot2h(__half2 a, __half2 b, float c) {
    h2v av, bv;
    __builtin_memcpy(&av, &a, 4);
    __builtin_memcpy(&bv, &b, 4);
    return __builtin_amdgcn_fdot2(av, bv, c, false);
}
#else
static __device__ __forceinline__ float dot2h(__half2 a, __half2 b, float c) {
    float2 fa = __half22float2(a), fb = __half22float2(b);
    return fmaf(fa.x, fb.x, fmaf(fa.y, fb.y, c));
}
#endif

#if __has_builtin(__builtin_amdgcn_exp2f)
#define EXP2F(x) __builtin_amdgcn_exp2f(x)
#else
#define EXP2F(x) exp2f(x)
#endif
#define LOG2E 1.4426950408889634f

// ---- cross-lane add helpers (VALU-pipe DPP where possible) ----
#define DPP_XOR1 0xB1   // quad_perm [1,0,3,2]
#define DPP_XOR2 0x4E   // quad_perm [2,3,0,1]
#define DPP_ROR4 0x124  // row_ror:4
#define DPP_ROR8 0x128  // row_ror:8

template <int CTRL>
static __device__ __forceinline__ float dpp_addf(float x) {
    const int y = __builtin_amdgcn_update_dpp(0, __float_as_int(x), CTRL, 0xf, 0xf, true);
    return x + __int_as_float(y);
}
static __device__ __forceinline__ float swz16_addf(float x) {   // xor 16
    const int y = __builtin_amdgcn_ds_swizzle(__float_as_int(x), 0x401f);
    return x + __int_as_float(y);
}
#if __has_builtin(__builtin_amdgcn_permlane32_swap)
static __device__ __forceinline__ float pl32_addf(float x) {    // xor 32
    typedef unsigned uv2 __attribute__((ext_vector_type(2)));
    const uv2 r = __builtin_amdgcn_permlane32_swap(__float_as_uint(x), __float_as_uint(x),
                                                   false, false);
    return __uint_as_float(r[0]) + __uint_as_float(r[1]);
}
#else
static __device__ __forceinline__ float pl32_addf(float x) { return x + __shfl_xor(x, 32); }
#endif

// ---- prepass: W fp32 [k][r][m][p] -> records {w01x,w23x,w01y,w23y} ----
// record j = (k*RR + r)*8 + p2, 4 half2 = 16 B.
__global__ __launch_bounds__(256)
void w_repack_kernel(const float* __restrict__ W, __half2* __restrict__ Wt)
{
    const int n = KK * RR * 8;                   // 37376 records
    for (int j = blockIdx.x * 256 + threadIdx.x; j < n; j += gridDim.x * 256) {
        const int p2 = j & 7;
        const int rk = j >> 3;                   // k*RR + r
        const float* wp = W + (size_t)rk * 64;   // [m][p], 64 floats
        const float x0 = wp[0*16 + 2*p2],     x1 = wp[1*16 + 2*p2];
        const float x2 = wp[2*16 + 2*p2],     x3 = wp[3*16 + 2*p2];
        const float y0 = wp[0*16 + 2*p2 + 1], y1 = wp[1*16 + 2*p2 + 1];
        const float y2 = wp[2*16 + 2*p2 + 1], y3 = wp[3*16 + 2*p2 + 1];
        __half2* o = Wt + (size_t)j * 4;
        o[0] = __floats2half2_rn(x0, x1);
        o[1] = __floats2half2_rn(x2, x3);
        o[2] = __floats2half2_rn(y0, y1);
        o[3] = __floats2half2_rn(y2, y3);
    }
}

// one stream's compute step (named scalars only)
#define STREAM_COMP(base, i, uu, wv)                                   \
    {                                                                  \
        const int r = (base) + (i) * 64 + rbase;                       \
        const __half2 u01 = __floats2half2_rn(uu.x, uu.y);             \
        const __half2 u23 = __floats2half2_rn(uu.z, uu.w);             \
        const __half2* hm = (const __half2*)&wv;                       \
        const float ax = dot2h(u01, hm[0], dot2h(u23, hm[1], 0.0f));   \
        const float ay = dot2h(u01, hm[2], dot2h(u23, hm[3], 0.0f));   \
        sA += ax; sB += ay;                                            \
        *(__half2*)(uji + r * 16 + p2 * 2) = __floats2half2_rn(ax, ay); \
    }

// one routing-sweep step over a 16B half-row held in rw
// (v2 is pre-scaled by log2e, so exp(d_true) == exp2(d))
#define SWEEP_STEP(rw)                                                     \
    {                                                                      \
        const __half2* hp = (const __half2*)&(rw);                         \
        float d = dot2h(hp[0], v2[0], dot2h(hp[1], v2[1],                  \
                  dot2h(hp[2], v2[2], dot2h(hp[3], v2[3], 0.0f))));        \
        d = dpp_addf<DPP_XOR1>(d);           /* join the two half-dots */  \
        const float e = EXP2F(d);            /* no max-subtract (bounded)*/\
        se += e;                                                           \
        { const float2 f0 = __half22float2(hp[0]);                         \
          s8[0] = fmaf(f0.x, e, s8[0]); s8[1] = fmaf(f0.y, e, s8[1]); }    \
        { const float2 f1 = __half22float2(hp[1]);                         \
          s8[2] = fmaf(f1.x, e, s8[2]); s8[3] = fmaf(f1.y, e, s8[3]); }    \
        { const float2 f2 = __half22float2(hp[2]);                         \
          s8[4] = fmaf(f2.x, e, s8[4]); s8[5] = fmaf(f2.y, e, s8[5]); }    \
        { const float2 f3 = __half22float2(hp[3]);                         \
          s8[6] = fmaf(f3.x, e, s8[6]); s8[7] = fmaf(f3.y, e, s8[7]); }    \
    }

__global__ __launch_bounds__(THREADS, 2)
void caps_routing_kernel(const float* __restrict__ u,
                         const __half2* __restrict__ Wt,
                         float* __restrict__ out)
{
    __shared__ __align__(16) __half uji[RR * 16];      // 74752 B
    __shared__ __align__(16) float  red[2][NWAVE][20]; // padded rows, f4-aligned
    __shared__ __align__(16) float  vrow[2][16];       // v vector hand-off

    const int bi   = blockIdx.x;                 // 2048 blocks
    const int b    = bi >> 1;
    const int k    = bi & 1;
    const int tid  = threadIdx.x;
    const int lane = tid & 63;
    const int wave = tid >> 6;
    const int p2   = lane & 7;                   // half2 column pair 0..7
    const int g    = lane >> 3;                  // row-in-group 0..7

    const float4* __restrict__ u4p = (const float4*)u;
    const float4* __restrict__ w4t = (const float4*)Wt + (size_t)k * RR * 8 + p2;

    // ---- build u_ji (fp16 -> LDS) + iter-0 sums; THREE-stream prefetch ----
    // streams A/B/C rows [0,768)/[768,1536)/[1536,2304), 12 steps each,
    // guard-free; tail rows 2304..2335 = waves 0..3 (wave-uniform).
    float sA = 0.0f, sB = 0.0f;
    {
        const int rbase = wave * 8 + g;
        float4 uuA_n = u4p[b * RR + rbase];
        float4 wvA_n = w4t[(size_t)rbase * 8];
        float4 uuB_n = u4p[b * RR + 768 + rbase];
        float4 wvB_n = w4t[(size_t)(768 + rbase) * 8];
        float4 uuC_n = u4p[b * RR + 1536 + rbase];
        float4 wvC_n = w4t[(size_t)(1536 + rbase) * 8];
        #pragma unroll 3
        for (int i = 0; i < 12; ++i) {
            const float4 uuA = uuA_n, wvA = wvA_n;
            const float4 uuB = uuB_n, wvB = wvB_n;
            const float4 uuC = uuC_n, wvC = wvC_n;
            if (i + 1 < 12) {                    // prefetch all three streams
                const int ra = (i + 1) * 64 + rbase;
                uuA_n = u4p[b * RR + ra];
                wvA_n = w4t[(size_t)ra * 8];
                const int rb = 768 + (i + 1) * 64 + rbase;
                uuB_n = u4p[b * RR + rb];
                wvB_n = w4t[(size_t)rb * 8];
                const int rc = 1536 + (i + 1) * 64 + rbase;
                uuC_n = u4p[b * RR + rc];
                wvC_n = w4t[(size_t)rc * 8];
            }
            STREAM_COMP(0,    i, uuA, wvA)
            STREAM_COMP(768,  i, uuB, wvB)
            STREAM_COMP(1536, i, uuC, wvC)
        }
        if (wave < 4) {                          // tail rows 2304..2335
            const int r = 2304 + rbase;
            const float4 uu = u4p[b * RR + r];
            const float4 wv = w4t[(size_t)r * 8];
            const __half2 u01 = __floats2half2_rn(uu.x, uu.y);
            const __half2 u23 = __floats2half2_rn(uu.z, uu.w);
            const __half2* hm = (const __half2*)&wv;
            const float ax = dot2h(u01, hm[0], dot2h(u23, hm[1], 0.0f));
            const float ay = dot2h(u01, hm[2], dot2h(u23, hm[3], 0.0f));
            sA += ax; sB += ay;
            *(__half2*)(uji + r * 16 + p2 * 2) = __floats2half2_rn(ax, ay);
        }
    }
    // iter-0 partials: reduce over g (xor8 -> DPP ror8, xor16 -> swizzle,
    // xor32 -> permlane32_swap; all preserve p2 = lane&7)
    sA = dpp_addf<DPP_ROR8>(sA);  sB = dpp_addf<DPP_ROR8>(sB);
    sA = swz16_addf(sA);          sB = swz16_addf(sB);
    sA = pl32_addf(sA);           sB = pl32_addf(sB);
    if (lane < 8) {
        red[0][wave][2 * p2]     = sA;
        red[0][wave][2 * p2 + 1] = sB;
    }
    __syncthreads();                             // barrier 1: uji + red[0] ready

    // ---- distributed squash, iter 0 (se == RR exactly); all-lane form ----
    float vcum_s;                                // this lane's cumulative v[lane&15]
    {
        float col = 0.0f;
        #pragma unroll
        for (int w = 0; w < NWAVE; ++w) col += red[0][w][lane & 15];
        float nr = col * col;
        nr = dpp_addf<DPP_XOR1>(nr);
        nr = dpp_addf<DPP_XOR2>(nr);
        nr = dpp_addf<DPP_ROR4>(nr);
        nr = dpp_addf<DPP_ROR8>(nr);             // row-replicated full 16-sum
        const float inv  = 1.0f / (float)RR;
        const float norm = nr * inv * inv;
        const float f    = sqrtf(norm) / (1.0f + norm);
        vcum_s = col * inv * f;
        if (lane < 16) vrow[0][lane] = vcum_s;   // benign same-value multi-wave write
    }

    // ---- iterations 1,2: sweep + distributed squash ----
    #pragma unroll 1
    for (int it = 1; it < 3; ++it) {
        const int buf = it & 1;

        __half2 v2[4];
        {
            const float2* vp = (const float2*)vrow[buf ^ 1];
            #pragma unroll
            for (int q = 0; q < 4; ++q) {
                const float2 pv = vp[(lane & 1) * 4 + q];
                v2[q] = __floats2half2_rn(pv.x * LOG2E, pv.y * LOG2E);
            }
        }

        // u_ji row slice: steps 0..8 guard-free (max row 2303); step 9 is
        // rows 2304..2335, loaded AND consumed only by wave 0.
        // Loaded per-iteration on purpose: hoisting costs ~16 live VGPRs
        // across the it-loop and tips the 64-VGPR occupancy cliff (r21).
        float4 raw[9];
        float4 raw9 = make_float4(0.0f, 0.0f, 0.0f, 0.0f);
        {
            const int rb = wave * 32 + (lane >> 1);
            #pragma unroll
            for (int s = 0; s < 9; ++s)
                raw[s] = *(const float4*)((const char*)uji + (s * 256 + rb) * 32 + (lane & 1) * 16);
            if (wave == 0)
                raw9 = *(const float4*)((const char*)uji + (2304 + (lane >> 1)) * 32 + (lane & 1) * 16);
        }

        float s8[8] = {0, 0, 0, 0, 0, 0, 0, 0};
        float se = 0.0f;
        #pragma unroll
        for (int s = 0; s < 9; ++s) SWEEP_STEP(raw[s])
        if (wave == 0) SWEEP_STEP(raw9)          // wave-uniform tail step

        // parity-preserving reduction: 3 DPP + 1 swizzle + 1 permlane per var
        #pragma unroll
        for (int i = 0; i < 8; ++i) {
            s8[i] = dpp_addf<DPP_XOR2>(s8[i]);
            s8[i] = dpp_addf<DPP_ROR4>(s8[i]);
            s8[i] = dpp_addf<DPP_ROR8>(s8[i]);
            s8[i] = swz16_addf(s8[i]);
            s8[i] = pl32_addf(s8[i]);
        }
        se = dpp_addf<DPP_XOR2>(se);
        se = dpp_addf<DPP_ROR4>(se);
        se = dpp_addf<DPP_ROR8>(se);
        se = swz16_addf(se);
        se = pl32_addf(se);

        if (lane < 2) {
            *(float4*)&red[buf][wave][(lane & 1) * 8]     = make_float4(s8[0], s8[1], s8[2], s8[3]);
            *(float4*)&red[buf][wave][(lane & 1) * 8 + 4] = make_float4(s8[4], s8[5], s8[6], s8[7]);
            if (lane == 0) red[buf][wave][16] = se;
        }
        __syncthreads();                         // barrier 2 / 3

        // distributed squash from red[buf] (all-lane form)
        {
            float col = 0.0f, set = 0.0f;
            #pragma unroll
            for (int w = 0; w < NWAVE; ++w) {
                col += red[buf][w][lane & 15];
                set += red[buf][w][16];          // broadcast reads
            }
            float nr = col * col;
            nr = dpp_addf<DPP_XOR1>(nr);
            nr = dpp_addf<DPP_XOR2>(nr);
            nr = dpp_addf<DPP_ROR4>(nr);
            nr = dpp_addf<DPP_ROR8>(nr);
            const float inv  = 1.0f / set;
            const float norm = nr * inv * inv;
            if (it == 1) {
                const float f = sqrtf(norm) / (1.0f + norm);
                vcum_s += col * inv * f;
                if (lane < 16) vrow[1][lane] = vcum_s;
            } else if (wave == 0 && lane == 0) {
                out[b * KK + k] = norm / (1.0f + norm);
            }
        }
    }
}

extern "C" void kernel_launch(void* const* d_in, const int* in_sizes, int n_in,
                              void* d_out, int out_size, void* d_ws, size_t ws_size,
                              hipStream_t stream) {
    const float* u = (const float*)d_in[0];   // [1024, 2336, 4]
    const float* W = (const float*)d_in[1];   // [2, 2336, 4, 16]
    float* out = (float*)d_out;               // [1024, 2]
    __half2* Wt = (__half2*)d_ws;             // W records scratch

    w_repack_kernel<<<dim3(256), dim3(256), 0, stream>>>(W, Wt);
    caps_routing_kernel<<<dim3(2048), dim3(THREADS), 0, stream>>>(u, Wt, out);
}